// Round 4
// baseline (369.255 us; speedup 1.0000x reference)
//
#include <hip/hip_runtime.h>
#include <math.h>

typedef _Float16 f16;
typedef _Float16 f16x8 __attribute__((ext_vector_type(8)));
typedef _Float16 f16x4 __attribute__((ext_vector_type(4)));
typedef float    f32x4 __attribute__((ext_vector_type(4)));

#define AS1 __attribute__((address_space(1)))
#define AS3 __attribute__((address_space(3)))

// scale folded into Q at qkv epilogue: 1/sqrt(64) * log2(e)
#define QSCALE 0.1803368800f

__device__ __forceinline__ void gload16(const void* g, void* l) {
    __builtin_amdgcn_global_load_lds((const AS1 void*)g, (AS3 void*)l, 16, 0, 0);
}

// ---------------------------------------------------------------------------
// cast x fp32 -> f16
// ---------------------------------------------------------------------------
__global__ __launch_bounds__(256) void cast_x_k(const float* __restrict__ in,
                                                f16* __restrict__ out, int n8)
{
    int i = blockIdx.x * 256 + threadIdx.x;
    const int stride = gridDim.x * 256;
    const float4* in4 = (const float4*)in;
    f16x8* o8 = (f16x8*)out;
    for (; i < n8; i += stride) {
        float4 a = in4[2 * i], b = in4[2 * i + 1];
        f16x8 o = {(f16)a.x, (f16)a.y, (f16)a.z, (f16)a.w,
                   (f16)b.x, (f16)b.y, (f16)b.z, (f16)b.w};
        o8[i] = o;
    }
}

// ---------------------------------------------------------------------------
// cast + transpose W [K][N] fp32 -> WT [N][K] f16
// ---------------------------------------------------------------------------
__global__ __launch_bounds__(256) void castT_k(const float* __restrict__ W,
                                               f16* __restrict__ WT, int K, int N)
{
    __shared__ float tile[32][33];
    const int k0 = blockIdx.y * 32, n0 = blockIdx.x * 32;
    const int t = threadIdx.x;
    const int r = t >> 3, cq = t & 7;
    float4 v = *(const float4*)&W[(size_t)(k0 + r) * N + n0 + cq * 4];
    tile[r][cq * 4 + 0] = v.x; tile[r][cq * 4 + 1] = v.y;
    tile[r][cq * 4 + 2] = v.z; tile[r][cq * 4 + 3] = v.w;
    __syncthreads();
    f16x4 pk = {(f16)tile[cq * 4 + 0][r], (f16)tile[cq * 4 + 1][r],
                (f16)tile[cq * 4 + 2][r], (f16)tile[cq * 4 + 3][r]};
    *(f16x4*)&WT[(size_t)(n0 + r) * K + k0 + cq * 4] = pk;
}

// ---------------------------------------------------------------------------
// f16 MFMA GEMM, 256x256 tile, BK=32, 4-slot LDS ring, counted vmcnt (T3/T4),
// setprio (T5). 512 threads = 8 waves (2M x 4N), per-wave 128x64 output.
// A [M][768], BT [N][768] f16 row-major. Per-wave loads/tile = 4, so
// vmcnt(12) == "3 newest tiles may be outstanding" -> tile kt landed.
// LDS linear, source-swizzled staging (chunk ^= row&3); reads undo the XOR.
// ---------------------------------------------------------------------------
#define GEMM_PIPE(APTR, BTPTR, NBN, PERX)                                        \
    __shared__ __align__(16) f16 As[4][256 * 32];                                \
    __shared__ __align__(16) f16 Bs[4][256 * 32];                                \
    const int t = threadIdx.x, lid = t & 63, wid = t >> 6;                       \
    const int wr = wid >> 2, wc = wid & 3;                                       \
    const int g = lid >> 4, cl = lid & 15;                                       \
    const int flat = blockIdx.x;                                                 \
    const int logical = (flat & 7) * (PERX) + (flat >> 3);                       \
    const int bm = logical / (NBN), bn = logical % (NBN);                        \
    f32x4 acc[8][4] = {};                                                        \
    const f16* aG[2]; const f16* bG[2]; int ldsoff[2];                           \
    _Pragma("unroll")                                                            \
    for (int i = 0; i < 2; ++i) {                                                \
        int c_lin = wid * 128 + i * 64 + lid;                                    \
        int row = c_lin >> 2, ch = c_lin & 3;                                    \
        int sch = ch ^ (row & 3);                                                \
        aG[i] = (APTR) + (size_t)(bm * 256 + row) * 768 + sch * 8;               \
        bG[i] = (BTPTR) + (size_t)(bn * 256 + row) * 768 + sch * 8;              \
        ldsoff[i] = (wid * 128 + i * 64) * 8;                                    \
    }                                                                            \
    _Pragma("unroll")                                                            \
    for (int p = 0; p < 3; ++p) {                                                \
        _Pragma("unroll")                                                        \
        for (int i = 0; i < 2; ++i) {                                            \
            gload16(aG[i] + p * 32, &As[p][ldsoff[i]]);                          \
            gload16(bG[i] + p * 32, &Bs[p][ldsoff[i]]);                          \
        }                                                                        \
    }                                                                            \
    for (int kt = 0; kt < 24; ++kt) {                                            \
        int tn = kt + 3; if (tn >= 24) tn -= 24;   /* wrap: dummy, never read */ \
        _Pragma("unroll")                                                        \
        for (int i = 0; i < 2; ++i) {                                            \
            gload16(aG[i] + tn * 32, &As[tn & 3][ldsoff[i]]);                    \
            gload16(bG[i] + tn * 32, &Bs[tn & 3][ldsoff[i]]);                    \
        }                                                                        \
        asm volatile("s_waitcnt vmcnt(12)" ::: "memory");                        \
        __builtin_amdgcn_s_barrier();                                            \
        const f16* As_ = &As[kt & 3][0];                                         \
        const f16* Bs_ = &Bs[kt & 3][0];                                         \
        const int slotx = (g ^ (cl & 3)) * 8;                                    \
        f16x8 af[8], bf[4];                                                      \
        _Pragma("unroll")                                                        \
        for (int m = 0; m < 8; ++m)                                              \
            af[m] = *(const f16x8*)&As_[(wr * 128 + m * 16 + cl) * 32 + slotx];  \
        _Pragma("unroll")                                                        \
        for (int n = 0; n < 4; ++n)                                              \
            bf[n] = *(const f16x8*)&Bs_[(wc * 64 + n * 16 + cl) * 32 + slotx];   \
        __builtin_amdgcn_s_setprio(1);                                           \
        _Pragma("unroll")                                                        \
        for (int m = 0; m < 8; ++m)                                              \
            _Pragma("unroll")                                                    \
            for (int n = 0; n < 4; ++n)                                          \
                acc[m][n] = __builtin_amdgcn_mfma_f32_16x16x32_f16(              \
                    af[m], bf[n], acc[m][n], 0, 0, 0);                           \
        __builtin_amdgcn_s_setprio(0);                                           \
        __builtin_amdgcn_s_barrier();                                            \
    }

__global__ __launch_bounds__(512, 2)
void qkv_gemm16(const f16* __restrict__ A, const f16* __restrict__ BT,
                const float* __restrict__ bias,
                f16* __restrict__ qws, f16* __restrict__ kws, f16* __restrict__ vt)
{
    GEMM_PIPE(A, BT, 9, 72)
#pragma unroll
    for (int m = 0; m < 8; ++m) {
        int rbase = bm * 256 + wr * 128 + m * 16 + g * 4;
#pragma unroll
        for (int n = 0; n < 4; ++n) {
            int cg = bn * 256 + wc * 64 + n * 16 + cl;
            float bb = bias[cg];
            int which = cg / 768;
            int rem = cg - which * 768;
            int h = rem >> 6, d = rem & 63;
            if (which == 2) {
                // V written directly transposed: VT [b*12+h][d][tok], 8B stores
                int b = rbase >> 10, tok = rbase & 1023;
                f16x4 pk = {(f16)(acc[m][n][0] + bb), (f16)(acc[m][n][1] + bb),
                            (f16)(acc[m][n][2] + bb), (f16)(acc[m][n][3] + bb)};
                *(f16x4*)&vt[((size_t)(b * 12 + h) * 64 + d) * 1024 + tok] = pk;
            } else {
                f16* dst = which ? kws : qws;
                float scl = which ? 1.0f : QSCALE;   // fold softmax scale+log2e into Q
#pragma unroll
                for (int r = 0; r < 4; ++r) {
                    int row = rbase + r;
                    int b = row >> 10, tok = row & 1023;
                    dst[((size_t)(b * 12 + h) * 1024 + tok) * 64 + d] =
                        (f16)((acc[m][n][r] + bb) * scl);
                }
            }
        }
    }
}

__global__ __launch_bounds__(512, 2)
void proj_gemm16(const f16* __restrict__ A, const f16* __restrict__ BT,
                 const float* __restrict__ bias, float* __restrict__ C)
{
    GEMM_PIPE(A, BT, 3, 24)
#pragma unroll
    for (int m = 0; m < 8; ++m) {
        int rbase = bm * 256 + wr * 128 + m * 16 + g * 4;
#pragma unroll
        for (int n = 0; n < 4; ++n) {
            int cg = bn * 256 + wc * 64 + n * 16 + cl;
            float bb = bias[cg];
#pragma unroll
            for (int r = 0; r < 4; ++r)
                C[(size_t)(rbase + r) * 768 + cg] = acc[m][n][r] + bb;
        }
    }
}

// ---------------------------------------------------------------------------
// MFMA flash attention with LDS-staged, double-buffered K/V tiles.
// Q pre-scaled by 1/8*log2e -> softmax uses exp2. Defer-max (T13, THR=8 in
// log2 domain; P <= 2^8 fits f16). setprio around MFMA clusters (T5).
// ---------------------------------------------------------------------------
__global__ __launch_bounds__(256)
void attn16(const f16* __restrict__ Q, const f16* __restrict__ K,
            const f16* __restrict__ VT, f16* __restrict__ AO)
{
    __shared__ __align__(16) f16 kbuf[2][64 * 64];
    __shared__ __align__(16) f16 vbuf[2][64 * 64];
    __shared__ __align__(16) f16 plds[4][16 * 64];

    const int t = threadIdx.x, lid = t & 63, wid = t >> 6;
    const int phys = blockIdx.y * gridDim.x + blockIdx.x;
    const int logical = (phys & 7) * 384 + (phys >> 3);
    const int bh = logical >> 4, qt = logical & 15;

    const int g = lid >> 4, c = lid & 15;
    const size_t hb = (size_t)bh * (1024 * 64);
    const int q0 = qt * 64 + wid * 16;

    const f16* qrow = Q + hb + (size_t)(q0 + c) * 64;
    const f16x8 qf0 = *(const f16x8*)(qrow + g * 8);
    const f16x8 qf1 = *(const f16x8*)(qrow + 32 + g * 8);

    const int srow   = wid * 16 + (lid >> 3);
    const int schunk = ((lid & 7) ^ (lid >> 3)) * 8;

#define ATTN_STAGE(BUF, KT)                                                      \
    {                                                                            \
        const f16* kb_ = K + hb + (size_t)((KT) * 64) * 64;                      \
        const f16* vb_ = VT + hb + (KT) * 64;                                    \
        _Pragma("unroll")                                                        \
        for (int c2 = 0; c2 < 2; ++c2) {                                         \
            gload16(kb_ + (size_t)(srow + c2 * 8) * 64 + schunk,                 \
                    &kbuf[BUF][wid * 1024 + c2 * 512]);                          \
            gload16(vb_ + (size_t)(srow + c2 * 8) * 1024 + schunk,               \
                    &vbuf[BUF][wid * 1024 + c2 * 512]);                          \
        }                                                                        \
    }

    f32x4 o[4] = {};
    float mrun = -INFINITY, lrun = 0.f;
    f16* myp = &plds[wid][0];

    ATTN_STAGE(0, 0)
    __syncthreads();

    int cur = 0;
    for (int kt = 0; kt < 16; ++kt) {
        if (kt < 15) ATTN_STAGE(cur ^ 1, kt + 1)

        const f16* kcur = &kbuf[cur][0];
        const f16* vcur = &vbuf[cur][0];
        const int sw = c & 7;

        f32x4 s[4] = {};
        __builtin_amdgcn_s_setprio(1);
#pragma unroll
        for (int m = 0; m < 4; ++m) {
            const int row = m * 16 + c;
            f16x8 k0f = *(const f16x8*)&kcur[row * 64 + ((g) ^ sw) * 8];
            f16x8 k1f = *(const f16x8*)&kcur[row * 64 + ((4 + g) ^ sw) * 8];
            s[m] = __builtin_amdgcn_mfma_f32_16x16x32_f16(k0f, qf0, s[m], 0, 0, 0);
            s[m] = __builtin_amdgcn_mfma_f32_16x16x32_f16(k1f, qf1, s[m], 0, 0, 0);
        }
        __builtin_amdgcn_s_setprio(0);

        // row-max (lane c owns q-row c; union over 4 g-lanes = 64 keys)
        float a0 = fmaxf(fmaxf(s[0][0], s[0][1]), fmaxf(s[0][2], s[0][3]));
        float a1 = fmaxf(fmaxf(s[1][0], s[1][1]), fmaxf(s[1][2], s[1][3]));
        float a2 = fmaxf(fmaxf(s[2][0], s[2][1]), fmaxf(s[2][2], s[2][3]));
        float a3 = fmaxf(fmaxf(s[3][0], s[3][1]), fmaxf(s[3][2], s[3][3]));
        float tmax = fmaxf(fmaxf(a0, a1), fmaxf(a2, a3));
        tmax = fmaxf(tmax, __shfl_xor(tmax, 16));
        tmax = fmaxf(tmax, __shfl_xor(tmax, 32));

        bool keep = __all(tmax - mrun <= 8.0f);     // first tile: -inf -> false
        float mnew = fmaxf(mrun, tmax);
        float mref = keep ? mrun : mnew;

        float ps = 0.f;
        float pe[4][4];
#pragma unroll
        for (int m = 0; m < 4; ++m)
#pragma unroll
            for (int r = 0; r < 4; ++r) {
                float p = __builtin_exp2f(s[m][r] - mref);
                pe[m][r] = p; ps += p;
            }
        ps += __shfl_xor(ps, 16);
        ps += __shfl_xor(ps, 32);

        if (keep) {
            lrun += ps;
        } else {
            float al = __builtin_exp2f(mrun - mnew);
            float al4[4];
#pragma unroll
            for (int r = 0; r < 4; ++r) al4[r] = __shfl(al, g * 4 + r);
#pragma unroll
            for (int n = 0; n < 4; ++n) {
                o[n][0] *= al4[0]; o[n][1] *= al4[1];
                o[n][2] *= al4[2]; o[n][3] *= al4[3];
            }
            lrun = lrun * al + ps;
            mrun = mnew;
        }

        // stage P -> swizzled per-wave LDS (8B writes)
#pragma unroll
        for (int m = 0; m < 4; ++m) {
            f16x4 pk = {(f16)pe[m][0], (f16)pe[m][1], (f16)pe[m][2], (f16)pe[m][3]};
            int slot = (2 * m + (g >> 1)) ^ sw;
            *(f16x4*)&myp[c * 64 + slot * 8 + (g & 1) * 4] = pk;
        }
        f16x8 pa[2];
#pragma unroll
        for (int kh = 0; kh < 2; ++kh) {
            int slot = (kh * 4 + g) ^ sw;
            pa[kh] = *(const f16x8*)&myp[c * 64 + slot * 8];
        }
        __builtin_amdgcn_s_setprio(1);
#pragma unroll
        for (int kh = 0; kh < 2; ++kh)
#pragma unroll
            for (int n = 0; n < 4; ++n) {
                const int row = n * 16 + c;
                f16x8 vf = *(const f16x8*)&vcur[row * 64 + ((kh * 4 + g) ^ sw) * 8];
                o[n] = __builtin_amdgcn_mfma_f32_16x16x32_f16(pa[kh], vf, o[n], 0, 0, 0);
            }
        __builtin_amdgcn_s_setprio(0);

        __syncthreads();   // drains stage vmcnt + all waves done with buf[cur]
        cur ^= 1;
    }

    float il = 1.0f / lrun;
    float il4[4];
#pragma unroll
    for (int r = 0; r < 4; ++r) il4[r] = __shfl(il, g * 4 + r);
    const int b = bh / 12, h = bh - b * 12;
#pragma unroll
    for (int n = 0; n < 4; ++n)
#pragma unroll
        for (int r = 0; r < 4; ++r) {
            int tok = q0 + g * 4 + r;
            AO[(size_t)(b * 1024 + tok) * 768 + h * 64 + n * 16 + c] =
                (f16)(o[n][r] * il4[r]);
        }
}

// ---------------------------------------------------------------------------

extern "C" void kernel_launch(void* const* d_in, const int* in_sizes, int n_in,
                              void* d_out, int out_size, void* d_ws, size_t ws_size,
                              hipStream_t stream)
{
    const float* x      = (const float*)d_in[0];
    const float* W_qkv  = (const float*)d_in[1];
    const float* b_qkv  = (const float*)d_in[2];
    const float* W_proj = (const float*)d_in[3];
    const float* b_proj = (const float*)d_in[4];
    float* out = (float*)d_out;

    const size_t per = (size_t)16 * 1024 * 768;   // 12,582,912
    f16* x16    = (f16*)d_ws;
    f16* wqkvT  = x16 + per;
    f16* wprojT = wqkvT + (size_t)768 * 2304;
    f16* qws    = wprojT + (size_t)768 * 768;
    f16* kws    = qws + per;
    f16* vt     = kws + per;
    f16* aws    = vt + per;

    cast_x_k<<<3072, 256, 0, stream>>>(x, x16, (int)(per / 8));
    castT_k<<<dim3(2304 / 32, 768 / 32), 256, 0, stream>>>(W_qkv, wqkvT, 768, 2304);
    castT_k<<<dim3(768 / 32, 768 / 32), 256, 0, stream>>>(W_proj, wprojT, 768, 768);
    qkv_gemm16<<<576, 512, 0, stream>>>(x16, wqkvT, b_qkv, qws, kws, vt);
    attn16<<<dim3(16, 192), 256, 0, stream>>>(qws, kws, vt, aws);
    proj_gemm16<<<192, 512, 0, stream>>>(aws, wprojT, b_proj, out);
}

// Round 5
// 357.095 us; speedup vs baseline: 1.0341x; 1.0341x over previous
//
#include <hip/hip_runtime.h>
#include <math.h>

typedef _Float16 f16;
typedef _Float16 f16x8 __attribute__((ext_vector_type(8)));
typedef _Float16 f16x4 __attribute__((ext_vector_type(4)));
typedef float    f32x4 __attribute__((ext_vector_type(4)));

#define AS1 __attribute__((address_space(1)))
#define AS3 __attribute__((address_space(3)))

// scale folded into Q at qkv epilogue: 1/sqrt(64) * log2(e)
#define QSCALE 0.1803368800f

__device__ __forceinline__ void gload16(const void* g, void* l) {
    __builtin_amdgcn_global_load_lds((const AS1 void*)g, (AS3 void*)l, 16, 0, 0);
}

// ---------------------------------------------------------------------------
// cast x fp32 -> f16
// ---------------------------------------------------------------------------
__global__ __launch_bounds__(256) void cast_x_k(const float* __restrict__ in,
                                                f16* __restrict__ out, int n8)
{
    int i = blockIdx.x * 256 + threadIdx.x;
    const int stride = gridDim.x * 256;
    const float4* in4 = (const float4*)in;
    f16x8* o8 = (f16x8*)out;
    for (; i < n8; i += stride) {
        float4 a = in4[2 * i], b = in4[2 * i + 1];
        f16x8 o = {(f16)a.x, (f16)a.y, (f16)a.z, (f16)a.w,
                   (f16)b.x, (f16)b.y, (f16)b.z, (f16)b.w};
        o8[i] = o;
    }
}

// ---------------------------------------------------------------------------
// cast + transpose W [K][N] fp32 -> WT [N][K] f16
// ---------------------------------------------------------------------------
__global__ __launch_bounds__(256) void castT_k(const float* __restrict__ W,
                                               f16* __restrict__ WT, int K, int N)
{
    __shared__ float tile[32][33];
    const int k0 = blockIdx.y * 32, n0 = blockIdx.x * 32;
    const int t = threadIdx.x;
    const int r = t >> 3, cq = t & 7;
    float4 v = *(const float4*)&W[(size_t)(k0 + r) * N + n0 + cq * 4];
    tile[r][cq * 4 + 0] = v.x; tile[r][cq * 4 + 1] = v.y;
    tile[r][cq * 4 + 2] = v.z; tile[r][cq * 4 + 3] = v.w;
    __syncthreads();
    f16x4 pk = {(f16)tile[cq * 4 + 0][r], (f16)tile[cq * 4 + 1][r],
                (f16)tile[cq * 4 + 2][r], (f16)tile[cq * 4 + 3][r]};
    *(f16x4*)&WT[(size_t)(n0 + r) * K + k0 + cq * 4] = pk;
}

// ---------------------------------------------------------------------------
// f16 MFMA GEMM, 128x128 tile, BK=64, 4 waves (2x2), 16x16x32 frags.
// 2-slot LDS double-buffer (64KB -> 2 blocks/CU) with counted vmcnt:
//   prologue: stage tile0
//   iter t:   stage tile t+1 -> slot (t+1)&1   (8 gload_lds/thread)
//             s_waitcnt vmcnt(8)  (own tile-t loads landed; t+1's in flight)
//             s_barrier           (everyone's tile-t loads visible)
//             ds_read + 32 MFMA (setprio) from slot t&1
//             s_barrier           (closes reads of slot t&1)
// LDS linear, source-swizzled staging (chunk ^= row&7); reads undo the XOR.
// ---------------------------------------------------------------------------
#define GEMM_MAIN(APTR, BTPTR)                                                   \
    __shared__ __align__(16) f16 As[2][128 * 64];                                \
    __shared__ __align__(16) f16 Bs[2][128 * 64];                                \
    const int t = threadIdx.x, lid = t & 63, wid = t >> 6;                       \
    const int wr = wid >> 1, wc = wid & 1;                                       \
    const int g = lid >> 4, cl = lid & 15;                                       \
    const int bm = blockIdx.y, bn = blockIdx.x;                                  \
    f32x4 acc[4][4] = {};                                                        \
    const int srow8 = lid >> 3;                                                  \
    const int sc = (lid & 7) ^ srow8;                                            \
    const f16* aG = (APTR) + (size_t)(bm * 128 + wid * 32 + srow8) * 768 + sc * 8;\
    const f16* bG = (BTPTR) + (size_t)(bn * 128 + wid * 32 + srow8) * 768 + sc * 8;\
    const int ldsoff = wid * 32 * 64;                                            \
    _Pragma("unroll")                                                            \
    for (int c = 0; c < 4; ++c) {                                                \
        gload16(aG + c * 8 * 768, &As[0][ldsoff + c * 8 * 64]);                  \
        gload16(bG + c * 8 * 768, &Bs[0][ldsoff + c * 8 * 64]);                  \
    }                                                                            \
    for (int kt = 0; kt < 12; ++kt) {                                            \
        const int tn = kt + 1;                                                   \
        if (tn < 12) {                                                           \
            _Pragma("unroll")                                                    \
            for (int c = 0; c < 4; ++c) {                                        \
                gload16(aG + c * 8 * 768 + tn * 64, &As[tn & 1][ldsoff + c * 8 * 64]); \
                gload16(bG + c * 8 * 768 + tn * 64, &Bs[tn & 1][ldsoff + c * 8 * 64]); \
            }                                                                    \
            asm volatile("s_waitcnt vmcnt(8)" ::: "memory");                     \
        } else {                                                                 \
            asm volatile("s_waitcnt vmcnt(0)" ::: "memory");                     \
        }                                                                        \
        __builtin_amdgcn_s_barrier();                                            \
        asm volatile("" ::: "memory");                                           \
        const f16* As_ = &As[kt & 1][0];                                         \
        const f16* Bs_ = &Bs[kt & 1][0];                                         \
        _Pragma("unroll")                                                        \
        for (int kh = 0; kh < 2; ++kh) {                                         \
            f16x8 af[4], bf[4];                                                  \
            _Pragma("unroll")                                                    \
            for (int m = 0; m < 4; ++m) {                                        \
                int row = wr * 64 + m * 16 + cl;                                 \
                int slot = (kh * 4 + g) ^ (row & 7);                             \
                af[m] = *(const f16x8*)&As_[row * 64 + slot * 8];                \
                int col = wc * 64 + m * 16 + cl;                                 \
                int slotb = (kh * 4 + g) ^ (col & 7);                            \
                bf[m] = *(const f16x8*)&Bs_[col * 64 + slotb * 8];               \
            }                                                                    \
            __builtin_amdgcn_s_setprio(1);                                       \
            _Pragma("unroll")                                                    \
            for (int m = 0; m < 4; ++m)                                          \
                _Pragma("unroll")                                                \
                for (int n = 0; n < 4; ++n)                                      \
                    acc[m][n] = __builtin_amdgcn_mfma_f32_16x16x32_f16(          \
                        af[m], bf[n], acc[m][n], 0, 0, 0);                       \
            __builtin_amdgcn_s_setprio(0);                                       \
        }                                                                        \
        asm volatile("" ::: "memory");                                           \
        __builtin_amdgcn_s_barrier();                                            \
    }

__global__ __launch_bounds__(256)
void qkv_gemm16(const f16* __restrict__ A, const f16* __restrict__ BT,
                const float* __restrict__ bias,
                f16* __restrict__ qws, f16* __restrict__ kws, f16* __restrict__ vt)
{
    GEMM_MAIN(A, BT)
#pragma unroll
    for (int m = 0; m < 4; ++m) {
        int rbase = bm * 128 + wr * 64 + m * 16 + g * 4;
#pragma unroll
        for (int n = 0; n < 4; ++n) {
            int cg = bn * 128 + wc * 64 + n * 16 + cl;
            float bb = bias[cg];
            int which = cg / 768;
            int rem = cg - which * 768;
            int h = rem >> 6, d = rem & 63;
            if (which == 2) {
                // V written directly transposed: VT [b*12+h][d][tok], 8B stores
                int b = rbase >> 10, tok = rbase & 1023;
                f16x4 pk = {(f16)(acc[m][n][0] + bb), (f16)(acc[m][n][1] + bb),
                            (f16)(acc[m][n][2] + bb), (f16)(acc[m][n][3] + bb)};
                *(f16x4*)&vt[((size_t)(b * 12 + h) * 64 + d) * 1024 + tok] = pk;
            } else {
                f16* dst = which ? kws : qws;
                float scl = which ? 1.0f : QSCALE;   // fold softmax scale+log2e into Q
#pragma unroll
                for (int r = 0; r < 4; ++r) {
                    int row = rbase + r;
                    int b = row >> 10, tok = row & 1023;
                    dst[((size_t)(b * 12 + h) * 1024 + tok) * 64 + d] =
                        (f16)((acc[m][n][r] + bb) * scl);
                }
            }
        }
    }
}

__global__ __launch_bounds__(256)
void proj_gemm16(const f16* __restrict__ A, const f16* __restrict__ BT,
                 const float* __restrict__ bias, float* __restrict__ C)
{
    GEMM_MAIN(A, BT)
#pragma unroll
    for (int m = 0; m < 4; ++m) {
        int rbase = bm * 128 + wr * 64 + m * 16 + g * 4;
#pragma unroll
        for (int n = 0; n < 4; ++n) {
            int cg = bn * 128 + wc * 64 + n * 16 + cl;
            float bb = bias[cg];
#pragma unroll
            for (int r = 0; r < 4; ++r)
                C[(size_t)(rbase + r) * 768 + cg] = acc[m][n][r] + bb;
        }
    }
}

// ---------------------------------------------------------------------------
// MFMA flash attention with LDS-staged, double-buffered K/V tiles.
// Q pre-scaled by 1/8*log2e -> softmax uses exp2. Defer-max (T13, THR=8 in
// log2 domain; P <= 2^8 fits f16). setprio around MFMA clusters (T5).
// ---------------------------------------------------------------------------
__global__ __launch_bounds__(256)
void attn16(const f16* __restrict__ Q, const f16* __restrict__ K,
            const f16* __restrict__ VT, f16* __restrict__ AO)
{
    __shared__ __align__(16) f16 kbuf[2][64 * 64];
    __shared__ __align__(16) f16 vbuf[2][64 * 64];
    __shared__ __align__(16) f16 plds[4][16 * 64];

    const int t = threadIdx.x, lid = t & 63, wid = t >> 6;
    const int phys = blockIdx.y * gridDim.x + blockIdx.x;
    const int logical = (phys & 7) * 384 + (phys >> 3);
    const int bh = logical >> 4, qt = logical & 15;

    const int g = lid >> 4, c = lid & 15;
    const size_t hb = (size_t)bh * (1024 * 64);
    const int q0 = qt * 64 + wid * 16;

    const f16* qrow = Q + hb + (size_t)(q0 + c) * 64;
    const f16x8 qf0 = *(const f16x8*)(qrow + g * 8);
    const f16x8 qf1 = *(const f16x8*)(qrow + 32 + g * 8);

    const int srow   = wid * 16 + (lid >> 3);
    const int schunk = ((lid & 7) ^ (lid >> 3)) * 8;

#define ATTN_STAGE(BUF, KT)                                                      \
    {                                                                            \
        const f16* kb_ = K + hb + (size_t)((KT) * 64) * 64;                      \
        const f16* vb_ = VT + hb + (KT) * 64;                                    \
        _Pragma("unroll")                                                        \
        for (int c2 = 0; c2 < 2; ++c2) {                                         \
            gload16(kb_ + (size_t)(srow + c2 * 8) * 64 + schunk,                 \
                    &kbuf[BUF][wid * 1024 + c2 * 512]);                          \
            gload16(vb_ + (size_t)(srow + c2 * 8) * 1024 + schunk,               \
                    &vbuf[BUF][wid * 1024 + c2 * 512]);                          \
        }                                                                        \
    }

    f32x4 o[4] = {};
    float mrun = -INFINITY, lrun = 0.f;
    f16* myp = &plds[wid][0];

    ATTN_STAGE(0, 0)
    __syncthreads();

    int cur = 0;
    for (int kt = 0; kt < 16; ++kt) {
        if (kt < 15) ATTN_STAGE(cur ^ 1, kt + 1)

        const f16* kcur = &kbuf[cur][0];
        const f16* vcur = &vbuf[cur][0];
        const int sw = c & 7;

        f32x4 s[4] = {};
        __builtin_amdgcn_s_setprio(1);
#pragma unroll
        for (int m = 0; m < 4; ++m) {
            const int row = m * 16 + c;
            f16x8 k0f = *(const f16x8*)&kcur[row * 64 + ((g) ^ sw) * 8];
            f16x8 k1f = *(const f16x8*)&kcur[row * 64 + ((4 + g) ^ sw) * 8];
            s[m] = __builtin_amdgcn_mfma_f32_16x16x32_f16(k0f, qf0, s[m], 0, 0, 0);
            s[m] = __builtin_amdgcn_mfma_f32_16x16x32_f16(k1f, qf1, s[m], 0, 0, 0);
        }
        __builtin_amdgcn_s_setprio(0);

        // row-max (lane c owns q-row c; union over 4 g-lanes = 64 keys)
        float a0 = fmaxf(fmaxf(s[0][0], s[0][1]), fmaxf(s[0][2], s[0][3]));
        float a1 = fmaxf(fmaxf(s[1][0], s[1][1]), fmaxf(s[1][2], s[1][3]));
        float a2 = fmaxf(fmaxf(s[2][0], s[2][1]), fmaxf(s[2][2], s[2][3]));
        float a3 = fmaxf(fmaxf(s[3][0], s[3][1]), fmaxf(s[3][2], s[3][3]));
        float tmax = fmaxf(fmaxf(a0, a1), fmaxf(a2, a3));
        tmax = fmaxf(tmax, __shfl_xor(tmax, 16));
        tmax = fmaxf(tmax, __shfl_xor(tmax, 32));

        bool keep = __all(tmax - mrun <= 8.0f);     // first tile: -inf -> false
        float mnew = fmaxf(mrun, tmax);
        float mref = keep ? mrun : mnew;

        float ps = 0.f;
        float pe[4][4];
#pragma unroll
        for (int m = 0; m < 4; ++m)
#pragma unroll
            for (int r = 0; r < 4; ++r) {
                float p = __builtin_exp2f(s[m][r] - mref);
                pe[m][r] = p; ps += p;
            }
        ps += __shfl_xor(ps, 16);
        ps += __shfl_xor(ps, 32);

        if (keep) {
            lrun += ps;
        } else {
            float al = __builtin_exp2f(mrun - mnew);
            float al4[4];
#pragma unroll
            for (int r = 0; r < 4; ++r) al4[r] = __shfl(al, g * 4 + r);
#pragma unroll
            for (int n = 0; n < 4; ++n) {
                o[n][0] *= al4[0]; o[n][1] *= al4[1];
                o[n][2] *= al4[2]; o[n][3] *= al4[3];
            }
            lrun = lrun * al + ps;
            mrun = mnew;
        }

        // stage P -> swizzled per-wave LDS (8B writes)
#pragma unroll
        for (int m = 0; m < 4; ++m) {
            f16x4 pk = {(f16)pe[m][0], (f16)pe[m][1], (f16)pe[m][2], (f16)pe[m][3]};
            int slot = (2 * m + (g >> 1)) ^ sw;
            *(f16x4*)&myp[c * 64 + slot * 8 + (g & 1) * 4] = pk;
        }
        f16x8 pa[2];
#pragma unroll
        for (int kh = 0; kh < 2; ++kh) {
            int slot = (kh * 4 + g) ^ sw;
            pa[kh] = *(const f16x8*)&myp[c * 64 + slot * 8];
        }
        __builtin_amdgcn_s_setprio(1);
#pragma unroll
        for (int kh = 0; kh < 2; ++kh)
#pragma unroll
            for (int n = 0; n < 4; ++n) {
                const int row = n * 16 + c;
                f16x8 vf = *(const f16x8*)&vcur[row * 64 + ((kh * 4 + g) ^ sw) * 8];
                o[n] = __builtin_amdgcn_mfma_f32_16x16x32_f16(pa[kh], vf, o[n], 0, 0, 0);
            }
        __builtin_amdgcn_s_setprio(0);

        __syncthreads();   // drains stage vmcnt + all waves done with buf[cur]
        cur ^= 1;
    }

    float il = 1.0f / lrun;
    float il4[4];
#pragma unroll
    for (int r = 0; r < 4; ++r) il4[r] = __shfl(il, g * 4 + r);
    const int b = bh / 12, h = bh - b * 12;
#pragma unroll
    for (int n = 0; n < 4; ++n)
#pragma unroll
        for (int r = 0; r < 4; ++r) {
            int tok = q0 + g * 4 + r;
            AO[(size_t)(b * 1024 + tok) * 768 + h * 64 + n * 16 + c] =
                (f16)(o[n][r] * il4[r]);
        }
}

// ---------------------------------------------------------------------------

extern "C" void kernel_launch(void* const* d_in, const int* in_sizes, int n_in,
                              void* d_out, int out_size, void* d_ws, size_t ws_size,
                              hipStream_t stream)
{
    const float* x      = (const float*)d_in[0];
    const float* W_qkv  = (const float*)d_in[1];
    const float* b_qkv  = (const float*)d_in[2];
    const float* W_proj = (const float*)d_in[3];
    const float* b_proj = (const float*)d_in[4];
    float* out = (float*)d_out;

    const size_t per = (size_t)16 * 1024 * 768;   // 12,582,912
    f16* x16    = (f16*)d_ws;
    f16* wqkvT  = x16 + per;
    f16* wprojT = wqkvT + (size_t)768 * 2304;
    f16* qws    = wprojT + (size_t)768 * 768;
    f16* kws    = qws + per;
    f16* vt     = kws + per;
    f16* aws    = vt + per;

    cast_x_k<<<3072, 256, 0, stream>>>(x, x16, (int)(per / 8));
    castT_k<<<dim3(2304 / 32, 768 / 32), 256, 0, stream>>>(W_qkv, wqkvT, 768, 2304);
    castT_k<<<dim3(768 / 32, 768 / 32), 256, 0, stream>>>(W_proj, wprojT, 768, 768);
    qkv_gemm16<<<dim3(18, 128), 256, 0, stream>>>(x16, wqkvT, b_qkv, qws, kws, vt);
    attn16<<<dim3(16, 192), 256, 0, stream>>>(qws, kws, vt, aws);
    proj_gemm16<<<dim3(6, 128), 256, 0, stream>>>(aws, wprojT, b_proj, out);
}

// Round 6
// 355.978 us; speedup vs baseline: 1.0373x; 1.0031x over previous
//
#include <hip/hip_runtime.h>
#include <math.h>

typedef _Float16 f16;
typedef _Float16 f16x8 __attribute__((ext_vector_type(8)));
typedef _Float16 f16x4 __attribute__((ext_vector_type(4)));
typedef float    f32x4 __attribute__((ext_vector_type(4)));

#define AS1 __attribute__((address_space(1)))
#define AS3 __attribute__((address_space(3)))

// scale folded into Q at qkv epilogue: 1/sqrt(64) * log2(e)  -> softmax via exp2
#define QSCALE 0.1803368800f

__device__ __forceinline__ void gload16(const void* g, void* l) {
    __builtin_amdgcn_global_load_lds((const AS1 void*)g, (AS3 void*)l, 16, 0, 0);
}

// ---------------------------------------------------------------------------
// cast x fp32 -> f16
// ---------------------------------------------------------------------------
__global__ __launch_bounds__(256) void cast_x_k(const float* __restrict__ in,
                                                f16* __restrict__ out, int n8)
{
    int i = blockIdx.x * 256 + threadIdx.x;
    const int stride = gridDim.x * 256;
    const float4* in4 = (const float4*)in;
    f16x8* o8 = (f16x8*)out;
    for (; i < n8; i += stride) {
        float4 a = in4[2 * i], b = in4[2 * i + 1];
        f16x8 o = {(f16)a.x, (f16)a.y, (f16)a.z, (f16)a.w,
                   (f16)b.x, (f16)b.y, (f16)b.z, (f16)b.w};
        o8[i] = o;
    }
}

// ---------------------------------------------------------------------------
// cast + transpose W [K][N] fp32 -> WT [N][K] f16
// ---------------------------------------------------------------------------
__global__ __launch_bounds__(256) void castT_k(const float* __restrict__ W,
                                               f16* __restrict__ WT, int K, int N)
{
    __shared__ float tile[32][33];
    const int k0 = blockIdx.y * 32, n0 = blockIdx.x * 32;
    const int t = threadIdx.x;
    const int r = t >> 3, cq = t & 7;
    float4 v = *(const float4*)&W[(size_t)(k0 + r) * N + n0 + cq * 4];
    tile[r][cq * 4 + 0] = v.x; tile[r][cq * 4 + 1] = v.y;
    tile[r][cq * 4 + 2] = v.z; tile[r][cq * 4 + 3] = v.w;
    __syncthreads();
    f16x4 pk = {(f16)tile[cq * 4 + 0][r], (f16)tile[cq * 4 + 1][r],
                (f16)tile[cq * 4 + 2][r], (f16)tile[cq * 4 + 3][r]};
    *(f16x4*)&WT[(size_t)(n0 + r) * K + k0 + cq * 4] = pk;
}

// ---------------------------------------------------------------------------
// f16 MFMA GEMM — round-3 structure (proven fastest so far): 128x128 tile,
// BK=64, 4 waves (2x2), single-buffered LDS, __syncthreads both sides.
// LDS linear, source-swizzled staging (chunk ^= row&7); reads undo the XOR.
// ---------------------------------------------------------------------------
#define GEMM_MAIN(APTR, BTPTR)                                                   \
    __shared__ __align__(16) f16 As[128 * 64];                                   \
    __shared__ __align__(16) f16 Bs[128 * 64];                                   \
    const int t = threadIdx.x, lid = t & 63, wid = t >> 6;                       \
    const int wr = wid >> 1, wc = wid & 1;                                       \
    const int g = lid >> 4, cl = lid & 15;                                       \
    const int bm = blockIdx.y, bn = blockIdx.x;                                  \
    f32x4 acc[4][4] = {};                                                        \
    const int srow8 = lid >> 3;                                                  \
    const int sc = (lid & 7) ^ srow8;                                            \
    const f16* aG = (APTR) + (size_t)(bm * 128 + wid * 32 + srow8) * 768 + sc * 8;\
    const f16* bG = (BTPTR) + (size_t)(bn * 128 + wid * 32 + srow8) * 768 + sc * 8;\
    f16* ldsA = As + wid * 32 * 64;                                              \
    f16* ldsB = Bs + wid * 32 * 64;                                              \
    for (int k0 = 0; k0 < 768; k0 += 64) {                                       \
        __syncthreads();                                                         \
        _Pragma("unroll")                                                        \
        for (int c = 0; c < 4; ++c) {                                            \
            gload16(aG + c * 8 * 768 + k0, ldsA + c * 8 * 64);                   \
            gload16(bG + c * 8 * 768 + k0, ldsB + c * 8 * 64);                   \
        }                                                                        \
        __syncthreads();                                                         \
        _Pragma("unroll")                                                        \
        for (int kh = 0; kh < 2; ++kh) {                                         \
            f16x8 af[4], bf[4];                                                  \
            _Pragma("unroll")                                                    \
            for (int m = 0; m < 4; ++m) {                                        \
                int row = wr * 64 + m * 16 + cl;                                 \
                int slot = (kh * 4 + g) ^ (row & 7);                             \
                af[m] = *(const f16x8*)&As[row * 64 + slot * 8];                 \
                int col = wc * 64 + m * 16 + cl;                                 \
                int slotb = (kh * 4 + g) ^ (col & 7);                            \
                bf[m] = *(const f16x8*)&Bs[col * 64 + slotb * 8];                \
            }                                                                    \
            _Pragma("unroll")                                                    \
            for (int m = 0; m < 4; ++m)                                          \
                _Pragma("unroll")                                                \
                for (int n = 0; n < 4; ++n)                                      \
                    acc[m][n] = __builtin_amdgcn_mfma_f32_16x16x32_f16(          \
                        af[m], bf[n], acc[m][n], 0, 0, 0);                       \
        }                                                                        \
    }

__global__ __launch_bounds__(256)
void qkv_gemm16(const f16* __restrict__ A, const f16* __restrict__ BT,
                const float* __restrict__ bias,
                f16* __restrict__ qws, f16* __restrict__ kws, f16* __restrict__ vt)
{
    GEMM_MAIN(A, BT)
#pragma unroll
    for (int m = 0; m < 4; ++m) {
        int rbase = bm * 128 + wr * 64 + m * 16 + g * 4;
#pragma unroll
        for (int n = 0; n < 4; ++n) {
            int cg = bn * 128 + wc * 64 + n * 16 + cl;
            float bb = bias[cg];
            int which = cg / 768;
            int rem = cg - which * 768;
            int h = rem >> 6, d = rem & 63;
            if (which == 2) {
                // V written directly transposed: VT [b*12+h][d][tok], 8B stores
                int b = rbase >> 10, tok = rbase & 1023;
                f16x4 pk = {(f16)(acc[m][n][0] + bb), (f16)(acc[m][n][1] + bb),
                            (f16)(acc[m][n][2] + bb), (f16)(acc[m][n][3] + bb)};
                *(f16x4*)&vt[((size_t)(b * 12 + h) * 64 + d) * 1024 + tok] = pk;
            } else {
                f16* dst = which ? kws : qws;
                float scl = which ? 1.0f : QSCALE;   // fold softmax scale+log2e into Q
#pragma unroll
                for (int r = 0; r < 4; ++r) {
                    int row = rbase + r;
                    int b = row >> 10, tok = row & 1023;
                    dst[((size_t)(b * 12 + h) * 1024 + tok) * 64 + d] =
                        (f16)((acc[m][n][r] + bb) * scl);
                }
            }
        }
    }
}

__global__ __launch_bounds__(256)
void proj_gemm16(const f16* __restrict__ A, const f16* __restrict__ BT,
                 const float* __restrict__ bias, float* __restrict__ C)
{
    GEMM_MAIN(A, BT)
#pragma unroll
    for (int m = 0; m < 4; ++m) {
        int rbase = bm * 128 + wr * 64 + m * 16 + g * 4;
#pragma unroll
        for (int n = 0; n < 4; ++n) {
            int cg = bn * 128 + wc * 64 + n * 16 + cl;
            float bb = bias[cg];
#pragma unroll
            for (int r = 0; r < 4; ++r)
                C[(size_t)(rbase + r) * 768 + cg] = acc[m][n][r] + bb;
        }
    }
}

// ---------------------------------------------------------------------------
// MFMA flash attention, 32 q-rows per wave (two 16-row groups sharing each
// K-frag and V-frag LDS read -> ~0.6x LDS traffic per unit work, half the
// barriers). Block = 128 q-rows of one (b,h); 4 waves. K/V tiles LDS-staged,
// double-buffered. exp2 softmax (scale+log2e pre-folded into Q).
// No setprio / no defer-max (both regressed in round 5).
// ---------------------------------------------------------------------------
__global__ __launch_bounds__(256)
void attn16(const f16* __restrict__ Q, const f16* __restrict__ K,
            const f16* __restrict__ VT, f16* __restrict__ AO)
{
    __shared__ __align__(16) f16 kbuf[2][64 * 64];
    __shared__ __align__(16) f16 vbuf[2][64 * 64];
    __shared__ __align__(16) f16 plds[4][2][16 * 64];

    const int t = threadIdx.x, lid = t & 63, wid = t >> 6;
    // 1536 blocks, 8 XCDs, 192/XCD; consecutive logical ids share a head's K/V.
    const int phys = blockIdx.y * gridDim.x + blockIdx.x;
    const int logical = (phys & 7) * 192 + (phys >> 3);
    const int bh = logical >> 3, qt = logical & 7;

    const int g = lid >> 4, c = lid & 15;
    const size_t hb = (size_t)bh * (1024 * 64);
    const int q0 = qt * 128 + wid * 32;

    const f16* qrowA = Q + hb + (size_t)(q0 + c) * 64;
    const f16* qrowB = qrowA + 16 * 64;
    const f16x8 qfA0 = *(const f16x8*)(qrowA + g * 8);
    const f16x8 qfA1 = *(const f16x8*)(qrowA + 32 + g * 8);
    const f16x8 qfB0 = *(const f16x8*)(qrowB + g * 8);
    const f16x8 qfB1 = *(const f16x8*)(qrowB + 32 + g * 8);

    const int srow   = wid * 16 + (lid >> 3);
    const int schunk = ((lid & 7) ^ (lid >> 3)) * 8;

#define ATTN_STAGE(BUF, KT)                                                      \
    {                                                                            \
        const f16* kb_ = K + hb + (size_t)((KT) * 64) * 64;                      \
        const f16* vb_ = VT + hb + (KT) * 64;                                    \
        _Pragma("unroll")                                                        \
        for (int c2 = 0; c2 < 2; ++c2) {                                         \
            gload16(kb_ + (size_t)(srow + c2 * 8) * 64 + schunk,                 \
                    &kbuf[BUF][wid * 1024 + c2 * 512]);                          \
            gload16(vb_ + (size_t)(srow + c2 * 8) * 1024 + schunk,               \
                    &vbuf[BUF][wid * 1024 + c2 * 512]);                          \
        }                                                                        \
    }

// online-softmax for one 16-row group: s[4] (f32x4) scores; updates m,l,o;
// stores exp'd P (f16) into MYP with the slot swizzle.
#define SOFTMAX_GRP(S, MRUN, LRUN, O, MYP)                                       \
    {                                                                            \
        float a0 = fmaxf(fmaxf(S[0][0], S[0][1]), fmaxf(S[0][2], S[0][3]));      \
        float a1 = fmaxf(fmaxf(S[1][0], S[1][1]), fmaxf(S[1][2], S[1][3]));      \
        float a2 = fmaxf(fmaxf(S[2][0], S[2][1]), fmaxf(S[2][2], S[2][3]));      \
        float a3 = fmaxf(fmaxf(S[3][0], S[3][1]), fmaxf(S[3][2], S[3][3]));      \
        float tmax = fmaxf(fmaxf(a0, a1), fmaxf(a2, a3));                        \
        tmax = fmaxf(tmax, __shfl_xor(tmax, 16));                                \
        tmax = fmaxf(tmax, __shfl_xor(tmax, 32));                                \
        float mnew = fmaxf(MRUN, tmax);                                          \
        float al = __builtin_exp2f(MRUN - mnew);                                 \
        float ps = 0.f;                                                          \
        float pe[4][4];                                                          \
        _Pragma("unroll")                                                        \
        for (int m = 0; m < 4; ++m)                                              \
            _Pragma("unroll")                                                    \
            for (int r = 0; r < 4; ++r) {                                        \
                float p = __builtin_exp2f(S[m][r] - mnew);                       \
                pe[m][r] = p; ps += p;                                           \
            }                                                                    \
        ps += __shfl_xor(ps, 16);                                                \
        ps += __shfl_xor(ps, 32);                                                \
        LRUN = LRUN * al + ps;                                                   \
        MRUN = mnew;                                                             \
        float al4[4];                                                            \
        _Pragma("unroll")                                                        \
        for (int r = 0; r < 4; ++r) al4[r] = __shfl(al, g * 4 + r);              \
        _Pragma("unroll")                                                        \
        for (int n = 0; n < 4; ++n) {                                            \
            O[n][0] *= al4[0]; O[n][1] *= al4[1];                                \
            O[n][2] *= al4[2]; O[n][3] *= al4[3];                                \
        }                                                                        \
        _Pragma("unroll")                                                        \
        for (int m = 0; m < 4; ++m) {                                            \
            f16x4 pk = {(f16)pe[m][0], (f16)pe[m][1],                            \
                        (f16)pe[m][2], (f16)pe[m][3]};                           \
            int slot = (2 * m + (g >> 1)) ^ sw;                                  \
            *(f16x4*)&(MYP)[c * 64 + slot * 8 + (g & 1) * 4] = pk;               \
        }                                                                        \
    }

    f32x4 oA[4] = {}, oB[4] = {};
    float mA = -INFINITY, lA = 0.f, mB = -INFINITY, lB = 0.f;
    f16* mypA = &plds[wid][0][0];
    f16* mypB = &plds[wid][1][0];

    ATTN_STAGE(0, 0)
    __syncthreads();

    int cur = 0;
    for (int kt = 0; kt < 16; ++kt) {
        if (kt < 15) ATTN_STAGE(cur ^ 1, kt + 1)

        const f16* kcur = &kbuf[cur][0];
        const f16* vcur = &vbuf[cur][0];
        const int sw = c & 7;

        // QK^T for both groups, one K-frag read serves both
        f32x4 sA[4] = {}, sB[4] = {};
#pragma unroll
        for (int m = 0; m < 4; ++m) {
            const int row = m * 16 + c;
            f16x8 k0f = *(const f16x8*)&kcur[row * 64 + ((g) ^ sw) * 8];
            f16x8 k1f = *(const f16x8*)&kcur[row * 64 + ((4 + g) ^ sw) * 8];
            sA[m] = __builtin_amdgcn_mfma_f32_16x16x32_f16(k0f, qfA0, sA[m], 0, 0, 0);
            sA[m] = __builtin_amdgcn_mfma_f32_16x16x32_f16(k1f, qfA1, sA[m], 0, 0, 0);
            sB[m] = __builtin_amdgcn_mfma_f32_16x16x32_f16(k0f, qfB0, sB[m], 0, 0, 0);
            sB[m] = __builtin_amdgcn_mfma_f32_16x16x32_f16(k1f, qfB1, sB[m], 0, 0, 0);
        }

        SOFTMAX_GRP(sA, mA, lA, oA, mypA)
        SOFTMAX_GRP(sB, mB, lB, oB, mypB)

        // P fragments
        f16x8 paA[2], paB[2];
#pragma unroll
        for (int kh = 0; kh < 2; ++kh) {
            int slot = (kh * 4 + g) ^ sw;
            paA[kh] = *(const f16x8*)&mypA[c * 64 + slot * 8];
            paB[kh] = *(const f16x8*)&mypB[c * 64 + slot * 8];
        }
        // PV: one V-frag read serves both groups
#pragma unroll
        for (int kh = 0; kh < 2; ++kh)
#pragma unroll
            for (int n = 0; n < 4; ++n) {
                const int row = n * 16 + c;
                f16x8 vf = *(const f16x8*)&vcur[row * 64 + ((kh * 4 + g) ^ sw) * 8];
                oA[n] = __builtin_amdgcn_mfma_f32_16x16x32_f16(paA[kh], vf, oA[n], 0, 0, 0);
                oB[n] = __builtin_amdgcn_mfma_f32_16x16x32_f16(paB[kh], vf, oB[n], 0, 0, 0);
            }

        __syncthreads();   // drains stage vmcnt + all waves done with buf[cur]
        cur ^= 1;
    }

    const int b = bh / 12, h = bh - b * 12;
    {
        float il = 1.0f / lA;
        float il4[4];
#pragma unroll
        for (int r = 0; r < 4; ++r) il4[r] = __shfl(il, g * 4 + r);
#pragma unroll
        for (int n = 0; n < 4; ++n)
#pragma unroll
            for (int r = 0; r < 4; ++r) {
                int tok = q0 + g * 4 + r;
                AO[(size_t)(b * 1024 + tok) * 768 + h * 64 + n * 16 + c] =
                    (f16)(oA[n][r] * il4[r]);
            }
    }
    {
        float il = 1.0f / lB;
        float il4[4];
#pragma unroll
        for (int r = 0; r < 4; ++r) il4[r] = __shfl(il, g * 4 + r);
#pragma unroll
        for (int n = 0; n < 4; ++n)
#pragma unroll
            for (int r = 0; r < 4; ++r) {
                int tok = q0 + 16 + g * 4 + r;
                AO[(size_t)(b * 1024 + tok) * 768 + h * 64 + n * 16 + c] =
                    (f16)(oB[n][r] * il4[r]);
            }
    }
}

// ---------------------------------------------------------------------------

extern "C" void kernel_launch(void* const* d_in, const int* in_sizes, int n_in,
                              void* d_out, int out_size, void* d_ws, size_t ws_size,
                              hipStream_t stream)
{
    const float* x      = (const float*)d_in[0];
    const float* W_qkv  = (const float*)d_in[1];
    const float* b_qkv  = (const float*)d_in[2];
    const float* W_proj = (const float*)d_in[3];
    const float* b_proj = (const float*)d_in[4];
    float* out = (float*)d_out;

    const size_t per = (size_t)16 * 1024 * 768;   // 12,582,912
    f16* x16    = (f16*)d_ws;
    f16* wqkvT  = x16 + per;
    f16* wprojT = wqkvT + (size_t)768 * 2304;
    f16* qws    = wprojT + (size_t)768 * 768;
    f16* kws    = qws + per;
    f16* vt     = kws + per;
    f16* aws    = vt + per;

    cast_x_k<<<3072, 256, 0, stream>>>(x, x16, (int)(per / 8));
    castT_k<<<dim3(2304 / 32, 768 / 32), 256, 0, stream>>>(W_qkv, wqkvT, 768, 2304);
    castT_k<<<dim3(768 / 32, 768 / 32), 256, 0, stream>>>(W_proj, wprojT, 768, 768);
    qkv_gemm16<<<dim3(18, 128), 256, 0, stream>>>(x16, wqkvT, b_qkv, qws, kws, vt);
    attn16<<<dim3(8, 192), 256, 0, stream>>>(qws, kws, vt, aws);
    proj_gemm16<<<dim3(6, 128), 256, 0, stream>>>(aws, wprojT, b_proj, out);
}

// Round 7
// 349.007 us; speedup vs baseline: 1.0580x; 1.0200x over previous
//
#include <hip/hip_runtime.h>
#include <math.h>

typedef _Float16 f16;
typedef _Float16 f16x8 __attribute__((ext_vector_type(8)));
typedef _Float16 f16x4 __attribute__((ext_vector_type(4)));
typedef float    f32x4 __attribute__((ext_vector_type(4)));

#define AS1 __attribute__((address_space(1)))
#define AS3 __attribute__((address_space(3)))

// scale folded into Q at qkv epilogue: 1/sqrt(64) * log2(e)  -> softmax via exp2
#define QSCALE 0.1803368800f

__device__ __forceinline__ void gload16(const void* g, void* l) {
    __builtin_amdgcn_global_load_lds((const AS1 void*)g, (AS3 void*)l, 16, 0, 0);
}

// ---------------------------------------------------------------------------
// cast x fp32 -> f16
// ---------------------------------------------------------------------------
__global__ __launch_bounds__(256) void cast_x_k(const float* __restrict__ in,
                                                f16* __restrict__ out, int n8)
{
    int i = blockIdx.x * 256 + threadIdx.x;
    const int stride = gridDim.x * 256;
    const float4* in4 = (const float4*)in;
    f16x8* o8 = (f16x8*)out;
    for (; i < n8; i += stride) {
        float4 a = in4[2 * i], b = in4[2 * i + 1];
        f16x8 o = {(f16)a.x, (f16)a.y, (f16)a.z, (f16)a.w,
                   (f16)b.x, (f16)b.y, (f16)b.z, (f16)b.w};
        o8[i] = o;
    }
}

// ---------------------------------------------------------------------------
// cast + transpose W [K][N] fp32 -> WT [N][K] f16
// ---------------------------------------------------------------------------
__global__ __launch_bounds__(256) void castT_k(const float* __restrict__ W,
                                               f16* __restrict__ WT, int K, int N)
{
    __shared__ float tile[32][33];
    const int k0 = blockIdx.y * 32, n0 = blockIdx.x * 32;
    const int t = threadIdx.x;
    const int r = t >> 3, cq = t & 7;
    float4 v = *(const float4*)&W[(size_t)(k0 + r) * N + n0 + cq * 4];
    tile[r][cq * 4 + 0] = v.x; tile[r][cq * 4 + 1] = v.y;
    tile[r][cq * 4 + 2] = v.z; tile[r][cq * 4 + 3] = v.w;
    __syncthreads();
    f16x4 pk = {(f16)tile[cq * 4 + 0][r], (f16)tile[cq * 4 + 1][r],
                (f16)tile[cq * 4 + 2][r], (f16)tile[cq * 4 + 3][r]};
    *(f16x4*)&WT[(size_t)(n0 + r) * K + k0 + cq * 4] = pk;
}

// ---------------------------------------------------------------------------
// f16 MFMA GEMM — round-3 structure (proven fastest so far): 128x128 tile,
// BK=64, 4 waves (2x2), single-buffered LDS, __syncthreads both sides.
// LDS linear, source-swizzled staging (chunk ^= row&7); reads undo the XOR.
// ---------------------------------------------------------------------------
#define GEMM_MAIN(APTR, BTPTR)                                                   \
    __shared__ __align__(16) f16 As[128 * 64];                                   \
    __shared__ __align__(16) f16 Bs[128 * 64];                                   \
    const int t = threadIdx.x, lid = t & 63, wid = t >> 6;                       \
    const int wr = wid >> 1, wc = wid & 1;                                       \
    const int g = lid >> 4, cl = lid & 15;                                       \
    const int bm = blockIdx.y, bn = blockIdx.x;                                  \
    f32x4 acc[4][4] = {};                                                        \
    const int srow8 = lid >> 3;                                                  \
    const int sc = (lid & 7) ^ srow8;                                            \
    const f16* aG = (APTR) + (size_t)(bm * 128 + wid * 32 + srow8) * 768 + sc * 8;\
    const f16* bG = (BTPTR) + (size_t)(bn * 128 + wid * 32 + srow8) * 768 + sc * 8;\
    f16* ldsA = As + wid * 32 * 64;                                              \
    f16* ldsB = Bs + wid * 32 * 64;                                              \
    for (int k0 = 0; k0 < 768; k0 += 64) {                                       \
        __syncthreads();                                                         \
        _Pragma("unroll")                                                        \
        for (int c = 0; c < 4; ++c) {                                            \
            gload16(aG + c * 8 * 768 + k0, ldsA + c * 8 * 64);                   \
            gload16(bG + c * 8 * 768 + k0, ldsB + c * 8 * 64);                   \
        }                                                                        \
        __syncthreads();                                                         \
        _Pragma("unroll")                                                        \
        for (int kh = 0; kh < 2; ++kh) {                                         \
            f16x8 af[4], bf[4];                                                  \
            _Pragma("unroll")                                                    \
            for (int m = 0; m < 4; ++m) {                                        \
                int row = wr * 64 + m * 16 + cl;                                 \
                int slot = (kh * 4 + g) ^ (row & 7);                             \
                af[m] = *(const f16x8*)&As[row * 64 + slot * 8];                 \
                int col = wc * 64 + m * 16 + cl;                                 \
                int slotb = (kh * 4 + g) ^ (col & 7);                            \
                bf[m] = *(const f16x8*)&Bs[col * 64 + slotb * 8];                \
            }                                                                    \
            _Pragma("unroll")                                                    \
            for (int m = 0; m < 4; ++m)                                          \
                _Pragma("unroll")                                                \
                for (int n = 0; n < 4; ++n)                                      \
                    acc[m][n] = __builtin_amdgcn_mfma_f32_16x16x32_f16(          \
                        af[m], bf[n], acc[m][n], 0, 0, 0);                       \
        }                                                                        \
    }

__global__ __launch_bounds__(256)
void qkv_gemm16(const f16* __restrict__ A, const f16* __restrict__ BT,
                const float* __restrict__ bias,
                f16* __restrict__ qws, f16* __restrict__ kws, f16* __restrict__ vt)
{
    GEMM_MAIN(A, BT)
#pragma unroll
    for (int m = 0; m < 4; ++m) {
        int rbase = bm * 128 + wr * 64 + m * 16 + g * 4;
#pragma unroll
        for (int n = 0; n < 4; ++n) {
            int cg = bn * 128 + wc * 64 + n * 16 + cl;
            float bb = bias[cg];
            int which = cg / 768;
            int rem = cg - which * 768;
            int h = rem >> 6, d = rem & 63;
            if (which == 2) {
                // V written directly transposed: VT [b*12+h][d][tok], 8B stores
                int b = rbase >> 10, tok = rbase & 1023;
                f16x4 pk = {(f16)(acc[m][n][0] + bb), (f16)(acc[m][n][1] + bb),
                            (f16)(acc[m][n][2] + bb), (f16)(acc[m][n][3] + bb)};
                *(f16x4*)&vt[((size_t)(b * 12 + h) * 64 + d) * 1024 + tok] = pk;
            } else {
                f16* dst = which ? kws : qws;
                float scl = which ? 1.0f : QSCALE;   // fold softmax scale+log2e into Q
#pragma unroll
                for (int r = 0; r < 4; ++r) {
                    int row = rbase + r;
                    int b = row >> 10, tok = row & 1023;
                    dst[((size_t)(b * 12 + h) * 1024 + tok) * 64 + d] =
                        (f16)((acc[m][n][r] + bb) * scl);
                }
            }
        }
    }
}

__global__ __launch_bounds__(256)
void proj_gemm16(const f16* __restrict__ A, const f16* __restrict__ BT,
                 const float* __restrict__ bias, float* __restrict__ C)
{
    GEMM_MAIN(A, BT)
#pragma unroll
    for (int m = 0; m < 4; ++m) {
        int rbase = bm * 128 + wr * 64 + m * 16 + g * 4;
#pragma unroll
        for (int n = 0; n < 4; ++n) {
            int cg = bn * 128 + wc * 64 + n * 16 + cl;
            float bb = bias[cg];
#pragma unroll
            for (int r = 0; r < 4; ++r)
                C[(size_t)(rbase + r) * 768 + cg] = acc[m][n][r] + bb;
        }
    }
}

// ---------------------------------------------------------------------------
// MFMA flash attention — round-5 geometry (proven best: 16 q-rows/wave,
// 4 waves/block, 40KB LDS, 3072 blocks), minus setprio and defer-max
// (measured ~+10us cost r3->r4), plus hoisted loop-invariant LDS offsets.
// exp2 softmax (scale+log2e pre-folded into Q at qkv epilogue).
// ---------------------------------------------------------------------------
__global__ __launch_bounds__(256)
void attn16(const f16* __restrict__ Q, const f16* __restrict__ K,
            const f16* __restrict__ VT, f16* __restrict__ AO)
{
    __shared__ __align__(16) f16 kbuf[2][64 * 64];
    __shared__ __align__(16) f16 vbuf[2][64 * 64];
    __shared__ __align__(16) f16 plds[4][16 * 64];

    const int t = threadIdx.x, lid = t & 63, wid = t >> 6;
    const int phys = blockIdx.y * gridDim.x + blockIdx.x;
    const int logical = (phys & 7) * 384 + (phys >> 3);
    const int bh = logical >> 4, qt = logical & 15;

    const int g = lid >> 4, c = lid & 15;
    const size_t hb = (size_t)bh * (1024 * 64);
    const int q0 = qt * 64 + wid * 16;

    const f16* qrow = Q + hb + (size_t)(q0 + c) * 64;
    const f16x8 qf0 = *(const f16x8*)(qrow + g * 8);
    const f16x8 qf1 = *(const f16x8*)(qrow + 32 + g * 8);

    const int srow   = wid * 16 + (lid >> 3);
    const int schunk = ((lid & 7) ^ (lid >> 3)) * 8;

#define ATTN_STAGE(BUF, KT)                                                      \
    {                                                                            \
        const f16* kb_ = K + hb + (size_t)((KT) * 64) * 64;                      \
        const f16* vb_ = VT + hb + (KT) * 64;                                    \
        _Pragma("unroll")                                                        \
        for (int c2 = 0; c2 < 2; ++c2) {                                         \
            gload16(kb_ + (size_t)(srow + c2 * 8) * 64 + schunk,                 \
                    &kbuf[BUF][wid * 1024 + c2 * 512]);                          \
            gload16(vb_ + (size_t)(srow + c2 * 8) * 1024 + schunk,               \
                    &vbuf[BUF][wid * 1024 + c2 * 512]);                          \
        }                                                                        \
    }

    // ---- hoisted, loop-invariant swizzled LDS element-offsets ----
    const int sw = c & 7;
    int koff[4][2], voff[2][4], poff[4], paoff[2];
#pragma unroll
    for (int m = 0; m < 4; ++m) {
        koff[m][0] = (m * 16 + c) * 64 + ((g) ^ sw) * 8;
        koff[m][1] = (m * 16 + c) * 64 + ((4 + g) ^ sw) * 8;
        poff[m]    = c * 64 + ((2 * m + (g >> 1)) ^ sw) * 8 + (g & 1) * 4;
    }
#pragma unroll
    for (int kh = 0; kh < 2; ++kh) {
        paoff[kh] = c * 64 + ((kh * 4 + g) ^ sw) * 8;
#pragma unroll
        for (int n = 0; n < 4; ++n)
            voff[kh][n] = (n * 16 + c) * 64 + ((kh * 4 + g) ^ sw) * 8;
    }

    f32x4 o[4] = {};
    float mrun = -INFINITY, lrun = 0.f;
    f16* myp = &plds[wid][0];

    ATTN_STAGE(0, 0)
    __syncthreads();

    int cur = 0;
    for (int kt = 0; kt < 16; ++kt) {
        if (kt < 15) ATTN_STAGE(cur ^ 1, kt + 1)

        const f16* kcur = &kbuf[cur][0];
        const f16* vcur = &vbuf[cur][0];

        f32x4 s[4] = {};
#pragma unroll
        for (int m = 0; m < 4; ++m) {
            f16x8 k0f = *(const f16x8*)&kcur[koff[m][0]];
            f16x8 k1f = *(const f16x8*)&kcur[koff[m][1]];
            s[m] = __builtin_amdgcn_mfma_f32_16x16x32_f16(k0f, qf0, s[m], 0, 0, 0);
            s[m] = __builtin_amdgcn_mfma_f32_16x16x32_f16(k1f, qf1, s[m], 0, 0, 0);
        }

        // online softmax for q-row (c); union over 4 g-lanes covers 64 keys
        float a0 = fmaxf(fmaxf(s[0][0], s[0][1]), fmaxf(s[0][2], s[0][3]));
        float a1 = fmaxf(fmaxf(s[1][0], s[1][1]), fmaxf(s[1][2], s[1][3]));
        float a2 = fmaxf(fmaxf(s[2][0], s[2][1]), fmaxf(s[2][2], s[2][3]));
        float a3 = fmaxf(fmaxf(s[3][0], s[3][1]), fmaxf(s[3][2], s[3][3]));
        float tmax = fmaxf(fmaxf(a0, a1), fmaxf(a2, a3));
        tmax = fmaxf(tmax, __shfl_xor(tmax, 16));
        tmax = fmaxf(tmax, __shfl_xor(tmax, 32));

        float mnew = fmaxf(mrun, tmax);
        float al = __builtin_exp2f(mrun - mnew);   // first tile: exp2(-inf)=0
        float ps = 0.f;
        float pe[4][4];
#pragma unroll
        for (int m = 0; m < 4; ++m)
#pragma unroll
            for (int r = 0; r < 4; ++r) {
                float p = __builtin_exp2f(s[m][r] - mnew);
                pe[m][r] = p; ps += p;
            }
        ps += __shfl_xor(ps, 16);
        ps += __shfl_xor(ps, 32);
        lrun = lrun * al + ps;
        mrun = mnew;

        // rescale O rows (rows g*4+r; alpha lives at lane (g*4+r))
        float al4[4];
#pragma unroll
        for (int r = 0; r < 4; ++r) al4[r] = __shfl(al, g * 4 + r);
#pragma unroll
        for (int n = 0; n < 4; ++n) {
            o[n][0] *= al4[0]; o[n][1] *= al4[1];
            o[n][2] *= al4[2]; o[n][3] *= al4[3];
        }

        // stage P -> swizzled per-wave LDS (8B writes)
#pragma unroll
        for (int m = 0; m < 4; ++m) {
            f16x4 pk = {(f16)pe[m][0], (f16)pe[m][1], (f16)pe[m][2], (f16)pe[m][3]};
            *(f16x4*)&myp[poff[m]] = pk;
        }
        f16x8 pa[2];
#pragma unroll
        for (int kh = 0; kh < 2; ++kh)
            pa[kh] = *(const f16x8*)&myp[paoff[kh]];

        // PV: A-frag from swizzled per-wave LDS, B-frag from staged V tile
#pragma unroll
        for (int kh = 0; kh < 2; ++kh)
#pragma unroll
            for (int n = 0; n < 4; ++n) {
                f16x8 vf = *(const f16x8*)&vcur[voff[kh][n]];
                o[n] = __builtin_amdgcn_mfma_f32_16x16x32_f16(pa[kh], vf, o[n], 0, 0, 0);
            }

        __syncthreads();   // drains stage vmcnt + all waves done with buf[cur]
        cur ^= 1;
    }

    float il = 1.0f / lrun;
    float il4[4];
#pragma unroll
    for (int r = 0; r < 4; ++r) il4[r] = __shfl(il, g * 4 + r);
    const int b = bh / 12, h = bh - b * 12;
#pragma unroll
    for (int n = 0; n < 4; ++n)
#pragma unroll
        for (int r = 0; r < 4; ++r) {
            int tok = q0 + g * 4 + r;
            AO[(size_t)(b * 1024 + tok) * 768 + h * 64 + n * 16 + c] =
                (f16)(o[n][r] * il4[r]);
        }
}

// ---------------------------------------------------------------------------

extern "C" void kernel_launch(void* const* d_in, const int* in_sizes, int n_in,
                              void* d_out, int out_size, void* d_ws, size_t ws_size,
                              hipStream_t stream)
{
    const float* x      = (const float*)d_in[0];
    const float* W_qkv  = (const float*)d_in[1];
    const float* b_qkv  = (const float*)d_in[2];
    const float* W_proj = (const float*)d_in[3];
    const float* b_proj = (const float*)d_in[4];
    float* out = (float*)d_out;

    const size_t per = (size_t)16 * 1024 * 768;   // 12,582,912
    f16* x16    = (f16*)d_ws;
    f16* wqkvT  = x16 + per;
    f16* wprojT = wqkvT + (size_t)768 * 2304;
    f16* qws    = wprojT + (size_t)768 * 768;
    f16* kws    = qws + per;
    f16* vt     = kws + per;
    f16* aws    = vt + per;

    cast_x_k<<<3072, 256, 0, stream>>>(x, x16, (int)(per / 8));
    castT_k<<<dim3(2304 / 32, 768 / 32), 256, 0, stream>>>(W_qkv, wqkvT, 768, 2304);
    castT_k<<<dim3(768 / 32, 768 / 32), 256, 0, stream>>>(W_proj, wprojT, 768, 768);
    qkv_gemm16<<<dim3(18, 128), 256, 0, stream>>>(x16, wqkvT, b_qkv, qws, kws, vt);
    attn16<<<dim3(16, 192), 256, 0, stream>>>(qws, kws, vt, aws);
    proj_gemm16<<<dim3(6, 128), 256, 0, stream>>>(aws, wprojT, b_proj, out);
}